// Round 1
// baseline (4555.708 us; speedup 1.0000x reference)
//
#include <hip/hip_runtime.h>
#include <math.h>

#define NA 100000
#define NE 800000
#define EPW 4

// ---- monotone float<->uint map for atomicMax on floats ----
__device__ __forceinline__ unsigned fmap(float f) {
    unsigned b = __float_as_uint(f);
    return (b & 0x80000000u) ? ~b : (b | 0x80000000u);
}
__device__ __forceinline__ float funmap(unsigned u) {
    unsigned b = (u & 0x80000000u) ? (u ^ 0x80000000u) : ~u;
    return __uint_as_float(b);
}

// ---- v = atom_feat @ Wv + bv  (N x 8) ----
__global__ void k_v(const float* __restrict__ af, const float* __restrict__ Wv,
                    const float* __restrict__ bv, float* __restrict__ v) {
    __shared__ float sWv[512];
    __shared__ float sbv[8];
    int t = threadIdx.x;
    for (int i = t; i < 512; i += 256) sWv[i] = Wv[i];
    if (t < 8) sbv[t] = bv[t];
    __syncthreads();
    int gid = blockIdx.x * 256 + t;
    if (gid >= NA * 8) return;
    int n = gid >> 3, i = gid & 7;
    const float* ar = af + (long)n * 64;
    float acc = sbv[i];
#pragma unroll
    for (int k = 0; k < 64; k++) acc += ar[k] * sWv[k * 8 + i];
    v[gid] = acc;
}

// ---- edge MLP: logits = relu(relu(x@W1+b1)@W2+b2)@W3+b3 ; atomic segmax ----
__global__ __launch_bounds__(256, 2) void k_edge_mlp(
    const float* __restrict__ af, const float* __restrict__ bond,
    const int* __restrict__ eidx,
    const float* __restrict__ W1, const float* __restrict__ b1,
    const float* __restrict__ W2, const float* __restrict__ b2,
    const float* __restrict__ W3, const float* __restrict__ b3,
    float* __restrict__ logits, unsigned* __restrict__ segmax) {
    __shared__ float sW1[192 * 64];   // 48 KB
    __shared__ float sW2[64 * 64];    // 16 KB  -> total exactly 64 KB
    int t = threadIdx.x;
    for (int i = t; i < 192 * 64; i += 256) sW1[i] = W1[i];
    for (int i = t; i < 64 * 64; i += 256) sW2[i] = W2[i];
    __syncthreads();

    int lane = t & 63, wv = t >> 6;
    float b1v = b1[lane];
    float b2v = b2[lane];
    float b3v = b3[lane & 7];
    float w3r[8];
#pragma unroll
    for (int o = 0; o < 8; o++) w3r[o] = W3[lane * 8 + o];

    long stride = (long)gridDim.x * 4 * EPW;
    for (long base = ((long)blockIdx.x * 4 + wv) * EPW; base < NE; base += stride) {
        long rem = NE - base;
        int ne = rem < EPW ? (int)rem : EPW;

        float xa[EPW], xb[EPW], xc[EPW];
        int srcs[EPW];
#pragma unroll
        for (int i = 0; i < EPW; i++) {
            if (i < ne) {
                long e = base + i;
                int2 sd = ((const int2*)eidx)[e];      // .x = src, .y = dst
                srcs[i] = sd.x;
                xa[i] = af[(long)sd.y * 64 + lane];    // atom_feat[dst]
                xb[i] = af[(long)sd.x * 64 + lane];    // atom_feat[src]
                xc[i] = bond[e * 64 + lane];
            } else {
                srcs[i] = 0; xa[i] = 0.f; xb[i] = 0.f; xc[i] = 0.f;
            }
        }

        float h1[EPW];
#pragma unroll
        for (int i = 0; i < EPW; i++) h1[i] = b1v;
#pragma unroll 4
        for (int k = 0; k < 64; k++) {
            float wA = sW1[k * 64 + lane];
            float wB = sW1[(64 + k) * 64 + lane];
            float wC = sW1[(128 + k) * 64 + lane];
#pragma unroll
            for (int i = 0; i < EPW; i++) {
                h1[i] += __shfl(xa[i], k) * wA;
                h1[i] += __shfl(xb[i], k) * wB;
                h1[i] += __shfl(xc[i], k) * wC;
            }
        }
#pragma unroll
        for (int i = 0; i < EPW; i++) h1[i] = fmaxf(h1[i], 0.f);

        float h2[EPW];
#pragma unroll
        for (int i = 0; i < EPW; i++) h2[i] = b2v;
#pragma unroll 4
        for (int k = 0; k < 64; k++) {
            float w = sW2[k * 64 + lane];
#pragma unroll
            for (int i = 0; i < EPW; i++) h2[i] += __shfl(h1[i], k) * w;
        }
#pragma unroll
        for (int i = 0; i < EPW; i++) h2[i] = fmaxf(h2[i], 0.f);

        for (int i = 0; i < ne; i++) {
            float p[8];
#pragma unroll
            for (int o = 0; o < 8; o++) p[o] = h2[i] * w3r[o];
#pragma unroll
            for (int s = 1; s < 64; s <<= 1) {
#pragma unroll
                for (int o = 0; o < 8; o++) p[o] += __shfl_xor(p[o], s);
            }
            long e = base + i;
#pragma unroll
            for (int o = 0; o < 8; o++) {
                if (lane == o) {
                    float lg = p[o] + b3v;   // b3v == b3[o] on lane o
                    logits[e * 8 + o] = lg;
                    atomicMax(&segmax[(long)srcs[i] * 8 + o], fmap(lg));
                }
            }
        }
    }
}

// ---- e = exp(logit - max); denom += e ----
__global__ void k_exp_denom(const int* __restrict__ eidx,
                            const float* __restrict__ logits,
                            const unsigned* __restrict__ segmax,
                            float* __restrict__ denom) {
    long gid = (long)blockIdx.x * 256 + threadIdx.x;
    if (gid >= (long)NE * 8) return;
    long e = gid >> 3;
    int o = gid & 7;
    int src = eidx[2 * e];
    float m = funmap(segmax[(long)src * 8 + o]);
    float ex = __expf(logits[gid] - m);
    atomicAdd(&denom[(long)src * 8 + o], ex);
}

// ---- agg[src] += att ⊗ v[dst]  (wave per edge, 64 atomics) ----
__global__ void k_agg(const int* __restrict__ eidx,
                      const float* __restrict__ logits,
                      const unsigned* __restrict__ segmax,
                      const float* __restrict__ denom,
                      const float* __restrict__ v,
                      float* __restrict__ agg) {
    int t = threadIdx.x;
    int lane = t & 63, wv = t >> 6;
    long e = (long)blockIdx.x * 4 + wv;
    if (e >= NE) return;
    int2 sd = ((const int2*)eidx)[e];
    int src = sd.x, dst = sd.y;
    int o = lane & 7;      // head index j
    int i = lane >> 3;     // value index
    float lg = logits[e * 8 + o];
    float m = funmap(segmax[(long)src * 8 + o]);
    float den = denom[(long)src * 8 + o];
    float att = __expf(lg - m) / den;
    float val = att * v[(long)dst * 8 + i];
    atomicAdd(&agg[(long)src * 64 + lane], val);
}

// ---- out_pre = agg@Wc+bc ; out_final = relu(af + out_pre) ----
__global__ __launch_bounds__(256) void k_out(
    const float* __restrict__ agg, const float* __restrict__ Wc,
    const float* __restrict__ bc, const float* __restrict__ af,
    float* __restrict__ out_pre, float* __restrict__ out_final) {
    __shared__ float sWc[64 * 64];
    int t = threadIdx.x;
    for (int i = t; i < 4096; i += 256) sWc[i] = Wc[i];
    __syncthreads();
    int lane = t & 63, wv = t >> 6;
    float bcv = bc[lane];
    long stride = (long)gridDim.x * 4;
    for (long n = (long)blockIdx.x * 4 + wv; n < NA; n += stride) {
        float a = agg[n * 64 + lane];
        float acc = bcv;
#pragma unroll 4
        for (int k = 0; k < 64; k++) acc += __shfl(a, k) * sWc[k * 64 + lane];
        out_pre[n * 64 + lane] = acc;
        out_final[n * 64 + lane] = fmaxf(af[n * 64 + lane] + acc, 0.f);
    }
}

// ---- new_bond = relu([out_pre[dst]+out_pre[src], bond] @ Wb + bb) ----
__global__ __launch_bounds__(256, 2) void k_bond_out(
    const float* __restrict__ out_pre, const float* __restrict__ bond,
    const int* __restrict__ eidx, const float* __restrict__ Wb,
    const float* __restrict__ bb, float* __restrict__ nbf) {
    __shared__ float sWb[128 * 64];   // 32 KB
    int t = threadIdx.x;
    for (int i = t; i < 8192; i += 256) sWb[i] = Wb[i];
    __syncthreads();
    int lane = t & 63, wv = t >> 6;
    float bbv = bb[lane];
    long stride = (long)gridDim.x * 4 * EPW;
    for (long base = ((long)blockIdx.x * 4 + wv) * EPW; base < NE; base += stride) {
        long rem = NE - base;
        int ne = rem < EPW ? (int)rem : EPW;
        float xs[EPW], xbd[EPW];
#pragma unroll
        for (int i = 0; i < EPW; i++) {
            if (i < ne) {
                long e = base + i;
                int2 sd = ((const int2*)eidx)[e];
                xs[i] = out_pre[(long)sd.x * 64 + lane] + out_pre[(long)sd.y * 64 + lane];
                xbd[i] = bond[e * 64 + lane];
            } else { xs[i] = 0.f; xbd[i] = 0.f; }
        }
        float acc[EPW];
#pragma unroll
        for (int i = 0; i < EPW; i++) acc[i] = bbv;
#pragma unroll 4
        for (int k = 0; k < 64; k++) {
            float wS = sWb[k * 64 + lane];
            float wB = sWb[(64 + k) * 64 + lane];
#pragma unroll
            for (int i = 0; i < EPW; i++) {
                acc[i] += __shfl(xs[i], k) * wS;
                acc[i] += __shfl(xbd[i], k) * wB;
            }
        }
        for (int i = 0; i < ne; i++)
            nbf[(base + i) * 64 + lane] = fmaxf(acc[i], 0.f);
    }
}

extern "C" void kernel_launch(void* const* d_in, const int* in_sizes, int n_in,
                              void* d_out, int out_size, void* d_ws, size_t ws_size,
                              hipStream_t stream) {
    const float* af   = (const float*)d_in[0];
    const float* bond = (const float*)d_in[1];
    const int*   eidx = (const int*)d_in[2];
    const float* Wv = (const float*)d_in[3];
    const float* bv = (const float*)d_in[4];
    const float* W1 = (const float*)d_in[5];
    const float* b1 = (const float*)d_in[6];
    const float* W2 = (const float*)d_in[7];
    const float* b2 = (const float*)d_in[8];
    const float* W3 = (const float*)d_in[9];
    const float* b3 = (const float*)d_in[10];
    const float* Wc = (const float*)d_in[11];
    const float* bc = (const float*)d_in[12];
    const float* Wb = (const float*)d_in[13];
    const float* bb = (const float*)d_in[14];

    float* out_final = (float*)d_out;              // N*64
    float* nbf       = (float*)d_out + (long)NA * 64;  // E*64

    // workspace layout (floats)
    float* ws = (float*)d_ws;
    float*    v       = ws;                         // N*8   = 800000
    unsigned* segmax  = (unsigned*)(ws + 800000);   // N*8
    float*    denom   = ws + 1600000;               // N*8
    float*    logits  = ws + 2400000;               // E*8   = 6.4M
    float*    agg     = ws + 8800000;               // N*64  = 6.4M
    float*    out_pre = ws + 15200000;              // N*64  = 6.4M

    // zero segmax+denom (contiguous) and agg — ws is poisoned before each call
    hipMemsetAsync((void*)segmax, 0, (size_t)1600000 * 4, stream);
    hipMemsetAsync((void*)agg, 0, (size_t)6400000 * 4, stream);

    k_v<<<(NA * 8 + 255) / 256, 256, 0, stream>>>(af, Wv, bv, v);

    k_edge_mlp<<<512, 256, 0, stream>>>(af, bond, eidx, W1, b1, W2, b2, W3, b3,
                                        logits, segmax);

    k_exp_denom<<<((long)NE * 8 + 255) / 256, 256, 0, stream>>>(eidx, logits,
                                                                segmax, denom);

    k_agg<<<NE / 4, 256, 0, stream>>>(eidx, logits, segmax, denom, v, agg);

    k_out<<<512, 256, 0, stream>>>(agg, Wc, bc, af, out_pre, out_final);

    k_bond_out<<<512, 256, 0, stream>>>(out_pre, bond, eidx, Wb, bb, nbf);
}

// Round 2
// 1052.538 us; speedup vs baseline: 4.3283x; 4.3283x over previous
//
#include <hip/hip_runtime.h>
#include <math.h>

#define NA 100000
#define NE 800000

typedef __attribute__((ext_vector_type(8))) short short8;
typedef __attribute__((ext_vector_type(4))) float f32x4;

// ---- monotone float<->uint map for atomicMax on floats ----
__device__ __forceinline__ unsigned fmap(float f) {
    unsigned b = __float_as_uint(f);
    return (b & 0x80000000u) ? ~b : (b | 0x80000000u);
}
__device__ __forceinline__ float funmap(unsigned u) {
    unsigned b = (u & 0x80000000u) ? (u ^ 0x80000000u) : ~u;
    return __uint_as_float(b);
}
// f32 -> bf16 RNE bits
__device__ __forceinline__ unsigned short f2bf(float f) {
    unsigned u = __float_as_uint(f);
    u += 0x7fffu + ((u >> 16) & 1u);
    return (unsigned short)(u >> 16);
}

__device__ __forceinline__ short8 ldsfrag(const unsigned short* p) {
    return *(const short8*)p;
}

// ---- v = atom_feat @ Wv + bv  (N x 8) ----
__global__ void k_v(const float* __restrict__ af, const float* __restrict__ Wv,
                    const float* __restrict__ bv, float* __restrict__ v) {
    __shared__ float sWv[512];
    __shared__ float sbv[8];
    int t = threadIdx.x;
    for (int i = t; i < 512; i += 256) sWv[i] = Wv[i];
    if (t < 8) sbv[t] = bv[t];
    __syncthreads();
    int gid = blockIdx.x * 256 + t;
    if (gid >= NA * 8) return;
    int n = gid >> 3, i = gid & 7;
    const float* ar = af + (long)n * 64;
    float acc = sbv[i];
#pragma unroll
    for (int k = 0; k < 64; k++) acc += ar[k] * sWv[k * 8 + i];
    v[gid] = acc;
}

// ---- edge MLP via MFMA: logits = relu(relu(x@W1+b1)@W2+b2)@W3+b3 ----
// wave processes 16 edges; x gathered into per-wave LDS in A-frag chunk order.
__global__ __launch_bounds__(256) void k_edge_mlp(
    const float* __restrict__ af, const float* __restrict__ bond,
    const int* __restrict__ eidx,
    const float* __restrict__ W1, const float* __restrict__ b1,
    const float* __restrict__ W2, const float* __restrict__ b2,
    const float* __restrict__ W3, const float* __restrict__ b3,
    float* __restrict__ logits, unsigned* __restrict__ segmax) {
    // B-fragment order: [n-tile][kchunk][n16][8k]
    __shared__ unsigned short sW1T[4][24][16][8];   // 24.0 KB
    __shared__ unsigned short sW2T[4][8][16][8];    //  8.0 KB
    __shared__ unsigned short sW3T[8][16][8];       //  2.0 KB
    __shared__ unsigned short sX[4][24][16][8];     // 24.0 KB (per-wave x / h)
    __shared__ int sED[4][16][2];                   // src,dst per staged edge

    int tid = threadIdx.x;
    // ---- stage weights (bf16, B-frag order) ----
    for (int idx = tid; idx < 192 * 64; idx += 256) {
        int k = idx >> 6, n = idx & 63;
        sW1T[n >> 4][k >> 3][n & 15][k & 7] = f2bf(W1[idx]);
    }
    for (int idx = tid; idx < 64 * 64; idx += 256) {
        int k = idx >> 6, n = idx & 63;
        sW2T[n >> 4][k >> 3][n & 15][k & 7] = f2bf(W2[idx]);
    }
    for (int idx = tid; idx < 8 * 16 * 8; idx += 256) ((unsigned short*)sW3T)[idx] = 0;
    __syncthreads();
    for (int idx = tid; idx < 64 * 8; idx += 256) {
        int k = idx >> 3, o = idx & 7;
        sW3T[k >> 3][o][k & 7] = f2bf(W3[idx]);
    }
    __syncthreads();

    int lane = tid & 63, wv = tid >> 6;
    int l15 = lane & 15, lq = lane >> 4;
    // per-lane loop-invariant biases (col n = t*16 + l15)
    float b1v[4], b2v[4];
#pragma unroll
    for (int t = 0; t < 4; t++) { b1v[t] = b1[t * 16 + l15]; b2v[t] = b2[t * 16 + l15]; }
    float b3v = (l15 < 8) ? b3[l15] : 0.f;

    long stride = (long)gridDim.x * 64;
    for (long base = ((long)blockIdx.x * 4 + wv) * 16; base < NE; base += stride) {
        // ---- stage edge indices ----
        if (lane < 16) {
            int2 sd = ((const int2*)eidx)[base + lane];
            sED[wv][lane][0] = sd.x;
            sED[wv][lane][1] = sd.y;
        }
        // ---- gather x (16 edges x 192 f32 -> bf16) into A-frag order ----
#pragma unroll
        for (int it = 0; it < 12; it++) {
            int q = it * 64 + lane;     // 0..767
            int e = q / 48;
            int r = q - e * 48;         // quad index within 192
            const float* sp;
            if (r < 16)      sp = af + (long)sED[wv][e][1] * 64 + r * 4;
            else if (r < 32) sp = af + (long)sED[wv][e][0] * 64 + (r - 16) * 4;
            else             sp = bond + (base + e) * 64 + (long)(r - 32) * 4;
            float4 xv = *(const float4*)sp;
            ushort4 p;
            p.x = f2bf(xv.x); p.y = f2bf(xv.y); p.z = f2bf(xv.z); p.w = f2bf(xv.w);
            *(ushort4*)&sX[wv][r >> 1][e][(r & 1) * 4] = p;
        }

        // ---- layer 1: x(16x192) @ W1 -> h1(16x64) ----
        f32x4 acc[4] = {{0,0,0,0},{0,0,0,0},{0,0,0,0},{0,0,0,0}};
#pragma unroll
        for (int ks = 0; ks < 6; ks++) {
            short8 a = ldsfrag(&sX[wv][ks * 4 + lq][l15][0]);
#pragma unroll
            for (int t = 0; t < 4; t++) {
                short8 b = ldsfrag(&sW1T[t][ks * 4 + lq][l15][0]);
                acc[t] = __builtin_amdgcn_mfma_f32_16x16x32_bf16(a, b, acc[t], 0, 0, 0);
            }
        }
        // relu+bias, write h1 back in A-frag order (x is dead)
#pragma unroll
        for (int t = 0; t < 4; t++)
#pragma unroll
            for (int r = 0; r < 4; r++) {
                float h = fmaxf(acc[t][r] + b1v[t], 0.f);
                sX[wv][2 * t + ((lane >> 3) & 1)][lq * 4 + r][lane & 7] = f2bf(h);
            }

        // ---- layer 2: h1(16x64) @ W2 -> h2(16x64) ----
        f32x4 acc2[4] = {{0,0,0,0},{0,0,0,0},{0,0,0,0},{0,0,0,0}};
#pragma unroll
        for (int ks = 0; ks < 2; ks++) {
            short8 a = ldsfrag(&sX[wv][ks * 4 + lq][l15][0]);
#pragma unroll
            for (int t = 0; t < 4; t++) {
                short8 b = ldsfrag(&sW2T[t][ks * 4 + lq][l15][0]);
                acc2[t] = __builtin_amdgcn_mfma_f32_16x16x32_bf16(a, b, acc2[t], 0, 0, 0);
            }
        }
#pragma unroll
        for (int t = 0; t < 4; t++)
#pragma unroll
            for (int r = 0; r < 4; r++) {
                float h = fmaxf(acc2[t][r] + b2v[t], 0.f);
                sX[wv][2 * t + ((lane >> 3) & 1)][lq * 4 + r][lane & 7] = f2bf(h);
            }

        // ---- layer 3: h2(16x64) @ W3 -> logits(16x8) ----
        f32x4 accL = {0, 0, 0, 0};
#pragma unroll
        for (int ks = 0; ks < 2; ks++) {
            short8 a = ldsfrag(&sX[wv][ks * 4 + lq][l15][0]);
            short8 b = ldsfrag(&sW3T[ks * 4 + lq][l15][0]);
            accL = __builtin_amdgcn_mfma_f32_16x16x32_bf16(a, b, accL, 0, 0, 0);
        }
        if (l15 < 8) {
#pragma unroll
            for (int r = 0; r < 4; r++) {
                int m = lq * 4 + r;
                float lg = accL[r] + b3v;
                long e = base + m;
                logits[e * 8 + l15] = lg;
                atomicMax(&segmax[(long)sED[wv][m][0] * 8 + l15], fmap(lg));
            }
        }
    }
}

// ---- e = exp(logit - max); denom += e ----
__global__ void k_exp_denom(const int* __restrict__ eidx,
                            const float* __restrict__ logits,
                            const unsigned* __restrict__ segmax,
                            float* __restrict__ denom) {
    long gid = (long)blockIdx.x * 256 + threadIdx.x;
    if (gid >= (long)NE * 8) return;
    long e = gid >> 3;
    int o = gid & 7;
    int src = eidx[2 * e];
    float m = funmap(segmax[(long)src * 8 + o]);
    float ex = __expf(logits[gid] - m);
    atomicAdd(&denom[(long)src * 8 + o], ex);
}

// ---- agg[src] += att ⊗ v[dst]  (wave per edge, 64 atomics) ----
__global__ void k_agg(const int* __restrict__ eidx,
                      const float* __restrict__ logits,
                      const unsigned* __restrict__ segmax,
                      const float* __restrict__ denom,
                      const float* __restrict__ v,
                      float* __restrict__ agg) {
    int t = threadIdx.x;
    int lane = t & 63, wv = t >> 6;
    long e = (long)blockIdx.x * 4 + wv;
    if (e >= NE) return;
    int2 sd = ((const int2*)eidx)[e];
    int src = sd.x, dst = sd.y;
    int o = lane & 7;      // head index j
    int i = lane >> 3;     // value index
    float lg = logits[e * 8 + o];
    float m = funmap(segmax[(long)src * 8 + o]);
    float den = denom[(long)src * 8 + o];
    float att = __expf(lg - m) / den;
    float val = att * v[(long)dst * 8 + i];
    atomicAdd(&agg[(long)src * 64 + lane], val);
}

// ---- out_pre = agg@Wc+bc ; out_final = relu(af + out_pre) ----
__global__ __launch_bounds__(256) void k_out(
    const float* __restrict__ agg, const float* __restrict__ Wc,
    const float* __restrict__ bc, const float* __restrict__ af,
    float* __restrict__ out_pre, float* __restrict__ out_final) {
    __shared__ float sWc[64 * 64];
    int t = threadIdx.x;
    for (int i = t; i < 4096; i += 256) sWc[i] = Wc[i];
    __syncthreads();
    int lane = t & 63, wv = t >> 6;
    float bcv = bc[lane];
    long stride = (long)gridDim.x * 4;
    for (long n = (long)blockIdx.x * 4 + wv; n < NA; n += stride) {
        float a = agg[n * 64 + lane];
        float acc = bcv;
#pragma unroll 4
        for (int k = 0; k < 64; k++) acc += __shfl(a, k) * sWc[k * 64 + lane];
        out_pre[n * 64 + lane] = acc;
        out_final[n * 64 + lane] = fmaxf(af[n * 64 + lane] + acc, 0.f);
    }
}

// ---- new_bond = relu([out_pre[dst]+out_pre[src], bond] @ Wb + bb) via MFMA ----
__global__ __launch_bounds__(256) void k_bond_out(
    const float* __restrict__ out_pre, const float* __restrict__ bond,
    const int* __restrict__ eidx, const float* __restrict__ Wb,
    const float* __restrict__ bb, float* __restrict__ nbf) {
    __shared__ unsigned short sWbT[4][16][16][8];   // 16 KB
    __shared__ unsigned short sXB[4][16][16][8];    // 16 KB (per-wave)
    __shared__ int sEDB[4][16][2];

    int tid = threadIdx.x;
    for (int idx = tid; idx < 128 * 64; idx += 256) {
        int k = idx >> 6, n = idx & 63;
        sWbT[n >> 4][k >> 3][n & 15][k & 7] = f2bf(Wb[idx]);
    }
    __syncthreads();

    int lane = tid & 63, wv = tid >> 6;
    int l15 = lane & 15, lq = lane >> 4;
    float bbv[4];
#pragma unroll
    for (int t = 0; t < 4; t++) bbv[t] = bb[t * 16 + l15];

    long stride = (long)gridDim.x * 64;
    for (long base = ((long)blockIdx.x * 4 + wv) * 16; base < NE; base += stride) {
        if (lane < 16) {
            int2 sd = ((const int2*)eidx)[base + lane];
            sEDB[wv][lane][0] = sd.x;
            sEDB[wv][lane][1] = sd.y;
        }
#pragma unroll
        for (int it = 0; it < 8; it++) {
            int q = it * 64 + lane;    // 0..511
            int e = q >> 5;
            int r = q & 31;            // quad index within 128
            float4 xv;
            if (r < 16) {
                const float4* pa = (const float4*)(out_pre + (long)sEDB[wv][e][1] * 64 + r * 4);
                const float4* pb = (const float4*)(out_pre + (long)sEDB[wv][e][0] * 64 + r * 4);
                float4 a = *pa, b = *pb;
                xv.x = a.x + b.x; xv.y = a.y + b.y; xv.z = a.z + b.z; xv.w = a.w + b.w;
            } else {
                xv = *(const float4*)(bond + (base + e) * 64 + (long)(r - 16) * 4);
            }
            ushort4 p;
            p.x = f2bf(xv.x); p.y = f2bf(xv.y); p.z = f2bf(xv.z); p.w = f2bf(xv.w);
            *(ushort4*)&sXB[wv][r >> 1][e][(r & 1) * 4] = p;
        }

        f32x4 acc[4] = {{0,0,0,0},{0,0,0,0},{0,0,0,0},{0,0,0,0}};
#pragma unroll
        for (int ks = 0; ks < 4; ks++) {
            short8 a = ldsfrag(&sXB[wv][ks * 4 + lq][l15][0]);
#pragma unroll
            for (int t = 0; t < 4; t++) {
                short8 b = ldsfrag(&sWbT[t][ks * 4 + lq][l15][0]);
                acc[t] = __builtin_amdgcn_mfma_f32_16x16x32_bf16(a, b, acc[t], 0, 0, 0);
            }
        }
#pragma unroll
        for (int t = 0; t < 4; t++)
#pragma unroll
            for (int r = 0; r < 4; r++) {
                long m = base + lq * 4 + r;
                nbf[m * 64 + t * 16 + l15] = fmaxf(acc[t][r] + bbv[t], 0.f);
            }
    }
}

extern "C" void kernel_launch(void* const* d_in, const int* in_sizes, int n_in,
                              void* d_out, int out_size, void* d_ws, size_t ws_size,
                              hipStream_t stream) {
    const float* af   = (const float*)d_in[0];
    const float* bond = (const float*)d_in[1];
    const int*   eidx = (const int*)d_in[2];
    const float* Wv = (const float*)d_in[3];
    const float* bv = (const float*)d_in[4];
    const float* W1 = (const float*)d_in[5];
    const float* b1 = (const float*)d_in[6];
    const float* W2 = (const float*)d_in[7];
    const float* b2 = (const float*)d_in[8];
    const float* W3 = (const float*)d_in[9];
    const float* b3 = (const float*)d_in[10];
    const float* Wc = (const float*)d_in[11];
    const float* bc = (const float*)d_in[12];
    const float* Wb = (const float*)d_in[13];
    const float* bb = (const float*)d_in[14];

    float* out_final = (float*)d_out;                  // N*64
    float* nbf       = (float*)d_out + (long)NA * 64;  // E*64

    float* ws = (float*)d_ws;
    float*    v       = ws;                         // N*8
    unsigned* segmax  = (unsigned*)(ws + 800000);   // N*8
    float*    denom   = ws + 1600000;               // N*8
    float*    logits  = ws + 2400000;               // E*8
    float*    agg     = ws + 8800000;               // N*64
    float*    out_pre = ws + 15200000;              // N*64

    hipMemsetAsync((void*)segmax, 0, (size_t)1600000 * 4, stream);
    hipMemsetAsync((void*)agg, 0, (size_t)6400000 * 4, stream);

    k_v<<<(NA * 8 + 255) / 256, 256, 0, stream>>>(af, Wv, bv, v);

    k_edge_mlp<<<512, 256, 0, stream>>>(af, bond, eidx, W1, b1, W2, b2, W3, b3,
                                        logits, segmax);

    k_exp_denom<<<((long)NE * 8 + 255) / 256, 256, 0, stream>>>(eidx, logits,
                                                                segmax, denom);

    k_agg<<<NE / 4, 256, 0, stream>>>(eidx, logits, segmax, denom, v, agg);

    k_out<<<512, 256, 0, stream>>>(agg, Wc, bc, af, out_pre, out_final);

    k_bond_out<<<1024, 256, 0, stream>>>(out_pre, bond, eidx, Wb, bb, nbf);
}